// Round 4
// baseline (67.661 us; speedup 1.0000x reference)
//
#include <hip/hip_runtime.h>
#include <hip/hip_bf16.h>

#define NI 256
#define NT 256
#define NL 25
#define NE 128
#define NHW 49
#define NPAD 64
#define NTL (NT*NL)   // 6400

typedef __attribute__((ext_vector_type(8))) short bf16x8;
typedef __attribute__((ext_vector_type(4))) float f32x4;

struct bf4 { __hip_bfloat16 x, y, z, w; };
struct bf2 { __hip_bfloat16 x, y; };

// ---- Kernel 1 (merged prep): blocks 0..799 gather text features,
//      blocks 800..1055 transpose image features ----
__global__ __launch_bounds__(256) void prep_kernel(
    const float* __restrict__ emb, const int* __restrict__ text,
    const float* __restrict__ img,
    __hip_bfloat16* __restrict__ tf, __hip_bfloat16* __restrict__ P)
{
    __shared__ float tile[NE * NHW];

    if (blockIdx.x < 800) {
        int idx = blockIdx.x * 256 + threadIdx.x;   // 4 elems each
        int tl = idx >> 5;
        int q  = idx & 31;
        int tok = text[tl];
        float4 v = *reinterpret_cast<const float4*>(emb + (size_t)tok * NE + q * 4);
        bf4 o { __float2bfloat16(v.x), __float2bfloat16(v.y),
                __float2bfloat16(v.z), __float2bfloat16(v.w) };
        *reinterpret_cast<bf4*>(tf + (size_t)tl * NE + q * 4) = o;
    } else {
        int i = blockIdx.x - 800;
        const float* src = img + (size_t)i * NE * NHW;
        for (int idx = threadIdx.x; idx < NE * NHW; idx += 256) tile[idx] = src[idx];
        __syncthreads();
        __hip_bfloat16* dst = P + (size_t)i * NPAD * NE;
        for (int idx = threadIdx.x; idx < NPAD * NE / 2; idx += 256) {
            int p = idx >> 6;
            int e = (idx & 63) * 2;
            bf2 o;
            if (p < NHW) {
                o.x = __float2bfloat16(tile[e * NHW + p]);
                o.y = __float2bfloat16(tile[(e + 1) * NHW + p]);
            } else {
                o.x = __float2bfloat16(0.f);
                o.y = o.x;
            }
            *reinterpret_cast<bf2*>(dst + p * NE + e) = o;
        }
    }
}

// ---- Kernel 2: fused MFMA GEMM (swapped operands) + deferred max/sum ----
// 1024 WGs = 64 image-groups x 16 text-chunks. Wave = 1 image (patches in
// 64 regs). Double-buffered B-frags, prefetch distance 2 tiles, no copies.
// Loop stores per-lane 16-patch partial maxes; epilogue does cross-lane max
// + length-25 sum (no shuffles / atomics in the hot loop).
__global__ __launch_bounds__(256, 4) void match_kernel(
    const __hip_bfloat16* __restrict__ tf,
    const __hip_bfloat16* __restrict__ P,
    const int* __restrict__ text_length,
    const float* __restrict__ logit_scale,
    float* __restrict__ out)
{
    __shared__ float vals[4][25][64];   // [wave][tile][lane] partial max

    const int ig   = blockIdx.x & 63;
    const int tq   = blockIdx.x >> 6;
    const int tid  = threadIdx.x;
    const int wave = tid >> 6;
    const int lane = tid & 63;
    const int lr   = lane & 15;
    const int lhi  = lane >> 4;

    // A-fragments: this wave's image, 64 patches x 128 k, resident.
    const int img = ig * 4 + wave;
    const __hip_bfloat16* Pi = P + (size_t)img * NPAD * NE;
    bf16x8 pfrag[4][4];
    #pragma unroll
    for (int m = 0; m < 4; m++) {
        const __hip_bfloat16* prow = Pi + (size_t)(m * 16 + lr) * NE + lhi * 8;
        #pragma unroll
        for (int k = 0; k < 4; k++)
            pfrag[m][k] = *reinterpret_cast<const bf16x8*>(prow + k * 32);
    }
    #pragma unroll
    for (int m = 0; m < 4; m++)
        #pragma unroll
        for (int k = 0; k < 4; k++)
            asm volatile("" : "+v"(pfrag[m][k]));

    // per-lane base into this chunk's text rows
    const __hip_bfloat16* Tl = tf + (size_t)tq * 400 * NE + (size_t)lr * NE + lhi * 8;

    bf16x8 A[4], B[4];
    #pragma unroll
    for (int k = 0; k < 4; k++) A[k] = *reinterpret_cast<const bf16x8*>(Tl + k * 32);
    #pragma unroll
    for (int k = 0; k < 4; k++) B[k] = *reinterpret_cast<const bf16x8*>(Tl + 16 * NE + k * 32);

    auto compute = [&](const bf16x8* T, int j) {
        f32x4 acc[4];
        #pragma unroll
        for (int m = 0; m < 4; m++) acc[m] = (f32x4){0.f, 0.f, 0.f, 0.f};
        #pragma unroll
        for (int k = 0; k < 4; k++)
            #pragma unroll
            for (int m = 0; m < 4; m++)
                acc[m] = __builtin_amdgcn_mfma_f32_16x16x32_bf16(
                    pfrag[m][k], T[k], acc[m], 0, 0, 0);
        // per-lane max over its 16 patches (rows m*16 + lhi*4 + r);
        // m=3: only patch 48 (lhi==0, reg 0) is real.
        float x0 = fmaxf(acc[0][0], acc[0][1]);
        float x1 = fmaxf(acc[0][2], acc[0][3]);
        float x2 = fmaxf(acc[1][0], acc[1][1]);
        float x3 = fmaxf(acc[1][2], acc[1][3]);
        float x4 = fmaxf(acc[2][0], acc[2][1]);
        float x5 = fmaxf(acc[2][2], acc[2][3]);
        float x6 = (lhi == 0) ? acc[3][0] : -3e38f;
        x0 = fmaxf(x0, x1);
        x2 = fmaxf(x2, x3);
        x4 = fmaxf(x4, x5);
        x0 = fmaxf(x0, x2);
        x4 = fmaxf(x4, x6);
        vals[wave][j][lane] = fmaxf(x0, x4);
    };

    #pragma unroll 1
    for (int jj = 0; jj < 12; jj++) {
        const int j0 = jj * 2;
        compute(A, j0);
        #pragma unroll
        for (int k = 0; k < 4; k++)
            A[k] = *reinterpret_cast<const bf16x8*>(Tl + (size_t)(j0 + 2) * 16 * NE + k * 32);
        compute(B, j0 + 1);
        const int jn = (j0 + 3 < 25) ? j0 + 3 : 24;   // last B-load is dead, clamp in-bounds
        #pragma unroll
        for (int k = 0; k < 4; k++)
            B[k] = *reinterpret_cast<const bf16x8*>(Tl + (size_t)jn * 16 * NE + k * 32);
    }
    compute(A, 24);

    __syncthreads();

    // Epilogue: cross-lane max + sum over L + scale; 64 outputs per WG.
    if (tid < 64) {
        int g  = tid >> 4;
        int tl = tid & 15;
        float s = 0.f;
        #pragma unroll
        for (int l = 0; l < 25; l++) {
            int row = tl * 25 + l;          // text row within chunk, 0..399
            int j = row >> 4;
            int r = row & 15;
            float m0 = fmaxf(vals[g][j][r],      vals[g][j][r + 16]);
            float m1 = fmaxf(vals[g][j][r + 32], vals[g][j][r + 48]);
            s += fmaxf(m0, m1);
        }
        int t = tq * 16 + tl;
        int i = ig * 4 + g;
        float val = s / (float)text_length[t] * expf(logit_scale[0]);
        out[(size_t)i * NT + t] = val;                      // logits_per_image [I,T]
        out[(size_t)NI * NT + (size_t)t * NI + i] = val;    // logits_per_text  [T,I]
    }
}

extern "C" void kernel_launch(void* const* d_in, const int* in_sizes, int n_in,
                              void* d_out, int out_size, void* d_ws, size_t ws_size,
                              hipStream_t stream)
{
    const float* img  = (const float*)d_in[0];   // [256,128,7,7]
    const float* emb  = (const float*)d_in[1];   // [10000,128]
    const float* ls   = (const float*)d_in[2];   // scalar
    const int*   text = (const int*)d_in[3];     // [256,25]
    const int*   tlen = (const int*)d_in[4];     // [256]
    float* out = (float*)d_out;

    __hip_bfloat16* tf = (__hip_bfloat16*)d_ws;                                 // 1,638,400 B
    __hip_bfloat16* P  = (__hip_bfloat16*)((char*)d_ws + (size_t)NTL * NE * 2); // 4,194,304 B

    prep_kernel<<<800 + NI, 256, 0, stream>>>(emb, text, img, tf, P);
    match_kernel<<<1024, 256, 0, stream>>>(tf, P, tlen, ls, out);
}

// Round 5
// 35.166 us; speedup vs baseline: 1.9240x; 1.9240x over previous
//
#include <hip/hip_runtime.h>
#include <hip/hip_bf16.h>
#include <stdint.h>

#define NI 256
#define NT 256
#define NL 25
#define NE 128
#define NHW 49
#define NTL (NT*NL)   // 6400

typedef __attribute__((ext_vector_type(8))) short bf16x8;
typedef __attribute__((ext_vector_type(4))) float f32x4;

__device__ __forceinline__ short f2bf(float x) {
    __hip_bfloat16 h = __float2bfloat16(x);
    return *reinterpret_cast<short*>(&h);
}

__device__ __forceinline__ void gload_lds16(const void* g, void* l) {
    __builtin_amdgcn_global_load_lds(
        (const __attribute__((address_space(1))) unsigned int*)g,
        (__attribute__((address_space(3))) unsigned int*)l, 16, 0, 0);
}

// ---- Prep: blocks 0..399 build tf2 (bf16, XOR-swizzled 16B chunks);
//      blocks 400..655 build P2 (patches in MFMA fragment-lane order) ----
// tf2 row r (256 B = 16 chunks): physical chunk c holds logical chunk c^(r&7).
// P2[i][mk][lane] (16 B): lane(lr=lane&15,lhi=lane>>4) holds patch (m*16+lr),
// elems k*32+lhi*8 .. +8, zero-padded for patch >= 49.
__global__ __launch_bounds__(256) void prep_kernel(
    const float* __restrict__ emb, const int* __restrict__ text,
    const float* __restrict__ img,
    __hip_bfloat16* __restrict__ tf2, __hip_bfloat16* __restrict__ P2)
{
    __shared__ float tile[NE * NHW];

    if (blockIdx.x < 400) {
        int idx = blockIdx.x * 256 + threadIdx.x;    // chunk id, 102400 total
        int r      = idx >> 4;
        int c_phys = idx & 15;
        int c_log  = c_phys ^ (r & 7);
        int tok = text[r];
        const float* src = emb + (size_t)tok * NE + c_log * 8;
        float4 a = *reinterpret_cast<const float4*>(src);
        float4 b = *reinterpret_cast<const float4*>(src + 4);
        bf16x8 o;
        o[0] = f2bf(a.x); o[1] = f2bf(a.y); o[2] = f2bf(a.z); o[3] = f2bf(a.w);
        o[4] = f2bf(b.x); o[5] = f2bf(b.y); o[6] = f2bf(b.z); o[7] = f2bf(b.w);
        *reinterpret_cast<bf16x8*>(tf2 + (size_t)r * NE + c_phys * 8) = o;
    } else {
        int i = blockIdx.x - 400;
        const float* src = img + (size_t)i * NE * NHW;
        for (int idx = threadIdx.x; idx < NE * NHW; idx += 256) tile[idx] = src[idx];
        __syncthreads();
        for (int idx = threadIdx.x; idx < 1024; idx += 256) {   // (mk, lane)
            int mk = idx >> 6, lane = idx & 63;
            int m = mk >> 2, k = mk & 3;
            int lr = lane & 15, lhi = lane >> 4;
            int p = m * 16 + lr;
            bf16x8 o;
            #pragma unroll
            for (int j = 0; j < 8; j++) {
                int e = k * 32 + lhi * 8 + j;
                o[j] = (p < NHW) ? f2bf(tile[e * NHW + p]) : (short)0;
            }
            *reinterpret_cast<bf16x8*>(P2 + ((size_t)(i * 16 + mk) * 64 + lane) * 8) = o;
        }
    }
}

// ---- Match: fused MFMA GEMM (swapped operands) + deferred max/sum ----
// 1024 WGs = 64 image-groups x 16 text-chunks; wave = 1 image (patches in
// 64 regs, loaded coalesced from P2). B text-tiles staged ONCE per WG into
// double-buffered LDS via global_load_lds (1 instr/wave/tile), XOR-swizzled
// for conflict-free ds_read_b128 fragments.
__global__ __launch_bounds__(256, 4) void match_kernel(
    const __hip_bfloat16* __restrict__ tf2,
    const __hip_bfloat16* __restrict__ P2,
    const int* __restrict__ text_length,
    const float* __restrict__ logit_scale,
    float* __restrict__ out)
{
    __shared__ __hip_bfloat16 Bbuf[2][16][NE];   // 2 x 4 KB, swizzled rows
    __shared__ float vals[4][25][64];            // [wave][tile][lane] partial max

    const int ig   = blockIdx.x & 63;
    const int tq   = blockIdx.x >> 6;
    const int tid  = threadIdx.x;
    const int wave = tid >> 6;
    const int lane = tid & 63;
    const int lr   = lane & 15;
    const int lhi  = lane >> 4;

    // pfrag: coalesced 1KB loads from fragment-order P2
    const int img = ig * 4 + wave;
    const bf16x8* p2 = reinterpret_cast<const bf16x8*>(P2) + (size_t)img * 16 * 64 + lane;
    bf16x8 pfrag[4][4];
    #pragma unroll
    for (int m = 0; m < 4; m++)
        #pragma unroll
        for (int k = 0; k < 4; k++)
            pfrag[m][k] = p2[(m * 4 + k) * 64];
    #pragma unroll
    for (int m = 0; m < 4; m++)
        #pragma unroll
        for (int k = 0; k < 4; k++)
            asm volatile("" : "+v"(pfrag[m][k]));

    // B staging: wave w loads rows w*4..w*4+3 (1 KB) of each 4 KB tile
    const char* tsrc = (const char*)tf2 + (size_t)tq * 400 * 256 + wave * 1024 + lane * 16;
    char* ldst0 = (char*)&Bbuf[0][0][0] + wave * 1024;
    char* ldst1 = (char*)&Bbuf[1][0][0] + wave * 1024;

    // fragment read offsets (loop-invariant, swizzle folded in)
    int boffs[4];
    #pragma unroll
    for (int k = 0; k < 4; k++)
        boffs[k] = (((k << 6) | (lhi << 4)) ^ ((lr & 7) << 4));
    const char* brow0 = (const char*)&Bbuf[0][0][0] + lr * 256;
    const char* brow1 = (const char*)&Bbuf[1][0][0] + lr * 256;

    auto compute = [&](const char* brow, int j) {
        bf16x8 bfrag[4];
        #pragma unroll
        for (int k = 0; k < 4; k++)
            bfrag[k] = *reinterpret_cast<const bf16x8*>(brow + boffs[k]);
        f32x4 acc[4];
        #pragma unroll
        for (int m = 0; m < 4; m++) acc[m] = (f32x4){0.f, 0.f, 0.f, 0.f};
        #pragma unroll
        for (int k = 0; k < 4; k++)
            #pragma unroll
            for (int m = 0; m < 4; m++)
                acc[m] = __builtin_amdgcn_mfma_f32_16x16x32_bf16(
                    pfrag[m][k], bfrag[k], acc[m], 0, 0, 0);
        // per-lane max over its 16 patches; m=3: only patch 48 (lhi==0, reg 0) real
        float x0 = fmaxf(acc[0][0], acc[0][1]);
        float x1 = fmaxf(acc[0][2], acc[0][3]);
        float x2 = fmaxf(acc[1][0], acc[1][1]);
        float x3 = fmaxf(acc[1][2], acc[1][3]);
        float x4 = fmaxf(acc[2][0], acc[2][1]);
        float x5 = fmaxf(acc[2][2], acc[2][3]);
        float x6 = (lhi == 0) ? acc[3][0] : -3e38f;
        x0 = fmaxf(x0, x1);
        x2 = fmaxf(x2, x3);
        x4 = fmaxf(x4, x5);
        x0 = fmaxf(x0, x2);
        x4 = fmaxf(x4, x6);
        vals[wave][j][lane] = fmaxf(x0, x4);
    };

    gload_lds16(tsrc, ldst0);   // tile 0 -> buf0

    #pragma unroll 1
    for (int jj = 0; jj < 12; jj++) {
        const int j0 = jj * 2;
        __syncthreads();                            // buf0 (tile j0) ready
        gload_lds16(tsrc + (size_t)(j0 + 1) * 4096, ldst1);
        compute(brow0, j0);
        __syncthreads();                            // buf1 (tile j0+1) ready
        gload_lds16(tsrc + (size_t)(j0 + 2) * 4096, ldst0);
        compute(brow1, j0 + 1);
    }
    __syncthreads();                                // buf0 (tile 24) ready
    compute(brow0, 24);
    __syncthreads();

    // Epilogue: cross-lane max + length-25 sum + scale; 64 outputs per WG.
    if (tid < 64) {
        int g  = tid >> 4;
        int tl = tid & 15;
        float s = 0.f;
        #pragma unroll
        for (int l = 0; l < 25; l++) {
            int row = tl * 25 + l;          // text row within chunk, 0..399
            int j = row >> 4;
            int r = row & 15;
            float m0 = fmaxf(vals[g][j][r],      vals[g][j][r + 16]);
            float m1 = fmaxf(vals[g][j][r + 32], vals[g][j][r + 48]);
            s += fmaxf(m0, m1);
        }
        int t = tq * 16 + tl;
        int i = ig * 4 + g;
        float val = s / (float)text_length[t] * expf(logit_scale[0]);
        out[(size_t)i * NT + t] = val;                      // logits_per_image [I,T]
        out[(size_t)NI * NT + (size_t)t * NI + i] = val;    // logits_per_text  [T,I]
    }
}

extern "C" void kernel_launch(void* const* d_in, const int* in_sizes, int n_in,
                              void* d_out, int out_size, void* d_ws, size_t ws_size,
                              hipStream_t stream)
{
    const float* img  = (const float*)d_in[0];   // [256,128,7,7]
    const float* emb  = (const float*)d_in[1];   // [10000,128]
    const float* ls   = (const float*)d_in[2];   // scalar
    const int*   text = (const int*)d_in[3];     // [256,25]
    const int*   tlen = (const int*)d_in[4];     // [256]
    float* out = (float*)d_out;

    __hip_bfloat16* tf2 = (__hip_bfloat16*)d_ws;                                  // 1,638,400 B
    __hip_bfloat16* P2  = (__hip_bfloat16*)((char*)d_ws + (size_t)NTL * NE * 2);  // 4,194,304 B

    prep_kernel<<<400 + NI, 256, 0, stream>>>(emb, text, img, tf2, P2);
    match_kernel<<<1024, 256, 0, stream>>>(tf2, P2, tlen, ls, out);
}

// Round 6
// 34.555 us; speedup vs baseline: 1.9581x; 1.0177x over previous
//
#include <hip/hip_runtime.h>
#include <hip/hip_bf16.h>
#include <stdint.h>

#define NI 256
#define NT 256
#define NL 25
#define NE 128
#define NHW 49
#define NTL (NT*NL)   // 6400

#define WAVES 8            // waves (=images) per match WG
#define CH_T 16            // texts per chunk
#define CH_ROWS 400        // CH_T * NL
#define CH_BYTES 102400    // CH_ROWS * 256

typedef __attribute__((ext_vector_type(8))) short bf16x8;
typedef __attribute__((ext_vector_type(4))) float f32x4;

__device__ __forceinline__ short f2bf(float x) {
    __hip_bfloat16 h = __float2bfloat16(x);
    return *reinterpret_cast<short*>(&h);
}

__device__ __forceinline__ void gload_lds16(const void* g, void* l) {
    __builtin_amdgcn_global_load_lds(
        (const __attribute__((address_space(1))) unsigned int*)g,
        (__attribute__((address_space(3))) unsigned int*)l, 16, 0, 0);
}

// ---- Prep: blocks 0..399 build tf2 (bf16, XOR-swizzled 16B chunks);
//      blocks 400..655 build P2 (patches in MFMA fragment-lane order) ----
// tf2 row r (256 B = 16 chunks): physical chunk c holds logical chunk c^(r&7).
// P2[i][mk][lane] (16 B): lane(lr,lhi) holds patch (m*16+lr), elems
// k*32+lhi*8..+8, zero-padded for patch >= 49.
__global__ __launch_bounds__(256) void prep_kernel(
    const float* __restrict__ emb, const int* __restrict__ text,
    const float* __restrict__ img,
    __hip_bfloat16* __restrict__ tf2, __hip_bfloat16* __restrict__ P2)
{
    __shared__ float tile[NE * NHW];

    if (blockIdx.x < 400) {
        int idx = blockIdx.x * 256 + threadIdx.x;    // chunk id, 102400 total
        int r      = idx >> 4;
        int c_phys = idx & 15;
        int c_log  = c_phys ^ (r & 7);
        int tok = text[r];
        const float* src = emb + (size_t)tok * NE + c_log * 8;
        float4 a = *reinterpret_cast<const float4*>(src);
        float4 b = *reinterpret_cast<const float4*>(src + 4);
        bf16x8 o;
        o[0] = f2bf(a.x); o[1] = f2bf(a.y); o[2] = f2bf(a.z); o[3] = f2bf(a.w);
        o[4] = f2bf(b.x); o[5] = f2bf(b.y); o[6] = f2bf(b.z); o[7] = f2bf(b.w);
        *reinterpret_cast<bf16x8*>(tf2 + (size_t)r * NE + c_phys * 8) = o;
    } else {
        int i = blockIdx.x - 400;
        const float4* src4 = reinterpret_cast<const float4*>(img + (size_t)i * NE * NHW);
        float4* tile4 = reinterpret_cast<float4*>(tile);
        for (int idx = threadIdx.x; idx < NE * NHW / 4; idx += 256) tile4[idx] = src4[idx];
        __syncthreads();
        for (int idx = threadIdx.x; idx < 1024; idx += 256) {   // (mk, lane)
            int mk = idx >> 6, lane = idx & 63;
            int m = mk >> 2, k = mk & 3;
            int lr = lane & 15, lhi = lane >> 4;
            int p = m * 16 + lr;
            bf16x8 o;
            #pragma unroll
            for (int j = 0; j < 8; j++) {
                int e = k * 32 + lhi * 8 + j;
                o[j] = (p < NHW) ? f2bf(tile[e * NHW + p]) : (short)0;
            }
            *reinterpret_cast<bf16x8*>(P2 + ((size_t)(i * 16 + mk) * 64 + lane) * 8) = o;
        }
    }
}

// ---- Match: fused MFMA GEMM (swapped operands) + deferred max/sum ----
// 512 WGs = 32 image-groups (8 images) x 16 text-chunks; 8 waves/WG, wave =
// 1 image (patches in 64 regs). Text tiles staged once per WG via
// global_load_lds, double-buffered in PAIRS (2 tiles per barrier) so each
// vmcnt-drain covers 256 wave-MFMAs.
__global__ __launch_bounds__(512, 2) void match_kernel(
    const __hip_bfloat16* __restrict__ tf2,
    const __hip_bfloat16* __restrict__ P2,
    const int* __restrict__ text_length,
    const float* __restrict__ logit_scale,
    float* __restrict__ out)
{
    __shared__ __hip_bfloat16 Bbuf[2][2][16][NE];   // [phase][tile-in-pair] 2x8 KB
    __shared__ float vals[WAVES][25][64];           // [wave][tile][lane] partial max

    const int ig   = blockIdx.x & 31;    // image group (8 images)
    const int tq   = blockIdx.x >> 5;    // text chunk (16 texts = 400 rows = 25 tiles)
    const int tid  = threadIdx.x;
    const int wave = tid >> 6;
    const int lane = tid & 63;
    const int lr   = lane & 15;
    const int lhi  = lane >> 4;

    // pfrag: coalesced 1KB loads from fragment-order P2
    const int img = ig * WAVES + wave;
    const bf16x8* p2 = reinterpret_cast<const bf16x8*>(P2) + (size_t)img * 16 * 64 + lane;
    bf16x8 pfrag[4][4];
    #pragma unroll
    for (int m = 0; m < 4; m++)
        #pragma unroll
        for (int k = 0; k < 4; k++)
            pfrag[m][k] = p2[(m * 4 + k) * 64];
    #pragma unroll
    for (int m = 0; m < 4; m++)
        #pragma unroll
        for (int k = 0; k < 4; k++)
            asm volatile("" : "+v"(pfrag[m][k]));

    const char* tsrc = (const char*)tf2 + (size_t)tq * CH_BYTES;
    char* lbase = (char*)&Bbuf[0][0][0][0];
    char* ldst  = lbase + wave * 1024;   // wave-uniform LDS dst (+lane*16 by HW)

    // stage pair p (tiles 2p, 2p+1 = 8 KB): each of 512 threads one 16B chunk.
    // Source clamped in-bounds (last pair's dead half re-reads tile 24; the
    // dupe lands in an unread LDS slot).
    auto stage = [&](int p) {
        int off = p * 8192 + tid * 16;
        off = off > (CH_BYTES - 16) ? (CH_BYTES - 16) : off;
        gload_lds16(tsrc + off, ldst + (p & 1) * 8192);
    };

    // fragment read offsets (swizzle folded in)
    int boffs[4];
    #pragma unroll
    for (int k = 0; k < 4; k++)
        boffs[k] = (((k << 6) | (lhi << 4)) ^ ((lr & 7) << 4));

    auto compute = [&](int ph, int slot, int j) {
        const char* brow = lbase + ph * 8192 + slot * 4096 + lr * 256;
        bf16x8 bfrag[4];
        #pragma unroll
        for (int k = 0; k < 4; k++)
            bfrag[k] = *reinterpret_cast<const bf16x8*>(brow + boffs[k]);
        f32x4 acc[4];
        #pragma unroll
        for (int m = 0; m < 4; m++) acc[m] = (f32x4){0.f, 0.f, 0.f, 0.f};
        #pragma unroll
        for (int k = 0; k < 4; k++)
            #pragma unroll
            for (int m = 0; m < 4; m++)
                acc[m] = __builtin_amdgcn_mfma_f32_16x16x32_bf16(
                    pfrag[m][k], bfrag[k], acc[m], 0, 0, 0);
        // per-lane max over its 16 patches; m=3: only patch 48 (lhi==0, reg 0) real
        float x0 = fmaxf(acc[0][0], acc[0][1]);
        float x1 = fmaxf(acc[0][2], acc[0][3]);
        float x2 = fmaxf(acc[1][0], acc[1][1]);
        float x3 = fmaxf(acc[1][2], acc[1][3]);
        float x4 = fmaxf(acc[2][0], acc[2][1]);
        float x5 = fmaxf(acc[2][2], acc[2][3]);
        float x6 = (lhi == 0) ? acc[3][0] : -3e38f;
        x0 = fmaxf(x0, x1);
        x2 = fmaxf(x2, x3);
        x4 = fmaxf(x4, x5);
        x0 = fmaxf(x0, x2);
        x4 = fmaxf(x4, x6);
        vals[wave][j][lane] = fmaxf(x0, x4);
    };

    stage(0);
    #pragma unroll 1
    for (int p = 0; p < 12; p++) {
        __syncthreads();            // pair p staged (vmcnt drained at barrier)
        stage(p + 1);               // issue next pair; latency hides under MFMA
        compute(p & 1, 0, 2 * p);
        compute(p & 1, 1, 2 * p + 1);
    }
    __syncthreads();                // pair 12 (tile 24) ready
    compute(0, 0, 24);
    __syncthreads();

    // Epilogue: cross-lane max + length-25 sum + scale; 128 outputs per WG.
    if (tid < 8 * CH_T) {
        int g  = tid >> 4;
        int tl = tid & 15;
        float s = 0.f;
        #pragma unroll
        for (int l = 0; l < 25; l++) {
            int row = tl * 25 + l;          // text row within chunk, 0..399
            int j = row >> 4;
            int r = row & 15;
            float m0 = fmaxf(vals[g][j][r],      vals[g][j][r + 16]);
            float m1 = fmaxf(vals[g][j][r + 32], vals[g][j][r + 48]);
            s += fmaxf(m0, m1);
        }
        int t = tq * CH_T + tl;
        int i = ig * WAVES + g;
        float val = s / (float)text_length[t] * expf(logit_scale[0]);
        out[(size_t)i * NT + t] = val;                      // logits_per_image [I,T]
        out[(size_t)NI * NT + (size_t)t * NI + i] = val;    // logits_per_text  [T,I]
    }
}

extern "C" void kernel_launch(void* const* d_in, const int* in_sizes, int n_in,
                              void* d_out, int out_size, void* d_ws, size_t ws_size,
                              hipStream_t stream)
{
    const float* img  = (const float*)d_in[0];   // [256,128,7,7]
    const float* emb  = (const float*)d_in[1];   // [10000,128]
    const float* ls   = (const float*)d_in[2];   // scalar
    const int*   text = (const int*)d_in[3];     // [256,25]
    const int*   tlen = (const int*)d_in[4];     // [256]
    float* out = (float*)d_out;

    __hip_bfloat16* tf2 = (__hip_bfloat16*)d_ws;                                  // 1,638,400 B
    __hip_bfloat16* P2  = (__hip_bfloat16*)((char*)d_ws + (size_t)NTL * NE * 2);  // 4,194,304 B

    prep_kernel<<<400 + NI, 256, 0, stream>>>(emb, text, img, tf2, P2);
    match_kernel<<<512, 512, 0, stream>>>(tf2, P2, tlen, ls, out);
}

// Round 7
// 33.920 us; speedup vs baseline: 1.9947x; 1.0187x over previous
//
#include <hip/hip_runtime.h>
#include <hip/hip_bf16.h>
#include <stdint.h>

#define NI 256
#define NT 256
#define NL 25
#define NE 128
#define NHW 49
#define NTL (NT*NL)   // 6400

#define WAVES 8            // waves (=images) per match WG
#define CH_T 16            // texts per chunk
#define CH_ROWS 400        // CH_T * NL
#define CH_BYTES 102400    // CH_ROWS * 256

typedef __attribute__((ext_vector_type(8))) short bf16x8;
typedef __attribute__((ext_vector_type(4))) float f32x4;

__device__ __forceinline__ short f2bf(float x) {
    __hip_bfloat16 h = __float2bfloat16(x);
    return *reinterpret_cast<short*>(&h);
}

__device__ __forceinline__ void gload_lds16(const void* g, void* l) {
    __builtin_amdgcn_global_load_lds(
        (const __attribute__((address_space(1))) unsigned int*)g,
        (__attribute__((address_space(3))) unsigned int*)l, 16, 0, 0);
}

// ---- Prep: blocks 0..399 build tf2 (bf16, XOR-swizzled 16B chunks);
//      blocks 400..655 build P2 (patches in MFMA fragment-lane order) ----
__global__ __launch_bounds__(256) void prep_kernel(
    const float* __restrict__ emb, const int* __restrict__ text,
    const float* __restrict__ img,
    __hip_bfloat16* __restrict__ tf2, __hip_bfloat16* __restrict__ P2)
{
    __shared__ float tile[NE * NHW];

    if (blockIdx.x < 400) {
        int idx = blockIdx.x * 256 + threadIdx.x;    // chunk id, 102400 total
        int r      = idx >> 4;
        int c_phys = idx & 15;
        int c_log  = c_phys ^ (r & 7);
        int tok = text[r];
        const float* src = emb + (size_t)tok * NE + c_log * 8;
        float4 a = *reinterpret_cast<const float4*>(src);
        float4 b = *reinterpret_cast<const float4*>(src + 4);
        bf16x8 o;
        o[0] = f2bf(a.x); o[1] = f2bf(a.y); o[2] = f2bf(a.z); o[3] = f2bf(a.w);
        o[4] = f2bf(b.x); o[5] = f2bf(b.y); o[6] = f2bf(b.z); o[7] = f2bf(b.w);
        *reinterpret_cast<bf16x8*>(tf2 + (size_t)r * NE + c_phys * 8) = o;
    } else {
        int i = blockIdx.x - 400;
        const float4* src4 = reinterpret_cast<const float4*>(img + (size_t)i * NE * NHW);
        float4* tile4 = reinterpret_cast<float4*>(tile);
        for (int idx = threadIdx.x; idx < NE * NHW / 4; idx += 256) tile4[idx] = src4[idx];
        __syncthreads();
        for (int idx = threadIdx.x; idx < 1024; idx += 256) {   // (mk, lane)
            int mk = idx >> 6, lane = idx & 63;
            int m = mk >> 2, k = mk & 3;
            int lr = lane & 15, lhi = lane >> 4;
            int p = m * 16 + lr;
            bf16x8 o;
            #pragma unroll
            for (int j = 0; j < 8; j++) {
                int e = k * 32 + lhi * 8 + j;
                o[j] = (p < NHW) ? f2bf(tile[e * NHW + p]) : (short)0;
            }
            *reinterpret_cast<bf16x8*>(P2 + ((size_t)(i * 16 + mk) * 64 + lane) * 8) = o;
        }
    }
}

// ---- Match: fused MFMA GEMM (swapped operands) + deferred max/sum ----
// 512 WGs = 32 image-groups (8 images) x 16 text-chunks; wave = 1 image.
// Ring-3 pair-buffers, staging depth 2, counted s_waitcnt vmcnt(1) + raw
// s_barrier per phase (never a full drain in the loop) — T3/T4 pattern.
__global__ __launch_bounds__(512, 4) void match_kernel(
    const __hip_bfloat16* __restrict__ tf2,
    const __hip_bfloat16* __restrict__ P2,
    const int* __restrict__ text_length,
    const float* __restrict__ logit_scale,
    float* __restrict__ out)
{
    __shared__ __hip_bfloat16 Bbuf[3][2][16][NE];   // 3 ring slots x 8 KB pair
    __shared__ float vals[WAVES][25][64];           // [wave][tile][lane] partial max

    const int ig   = blockIdx.x & 31;    // image group (8 images)
    const int tq   = blockIdx.x >> 5;    // text chunk (16 texts = 400 rows = 25 tiles)
    const int tid  = threadIdx.x;
    const int wave = tid >> 6;
    const int lane = tid & 63;
    const int lr   = lane & 15;
    const int lhi  = lane >> 4;

    // pfrag: coalesced 1KB loads from fragment-order P2
    const int img = ig * WAVES + wave;
    const bf16x8* p2 = reinterpret_cast<const bf16x8*>(P2) + (size_t)img * 16 * 64 + lane;
    bf16x8 pfrag[4][4];
    #pragma unroll
    for (int m = 0; m < 4; m++)
        #pragma unroll
        for (int k = 0; k < 4; k++)
            pfrag[m][k] = p2[(m * 4 + k) * 64];
    #pragma unroll
    for (int m = 0; m < 4; m++)
        #pragma unroll
        for (int k = 0; k < 4; k++)
            asm volatile("" : "+v"(pfrag[m][k]));   // forces completion + residency

    const char* tsrc = (const char*)tf2 + (size_t)tq * CH_BYTES;
    char* lbase = (char*)&Bbuf[0][0][0][0];
    char* ldst  = lbase + wave * 1024;   // wave-uniform LDS dst (+lane*16 by HW)

    // stage pair p (8 KB = tiles 2p,2p+1): 512 threads x 16B. Source clamped
    // in-bounds (pair 12's dead half re-reads tail; lands in an unread slot).
    auto stage = [&](int p) {
        int off = p * 8192 + tid * 16;
        off = off > (CH_BYTES - 16) ? (CH_BYTES - 16) : off;
        gload_lds16(tsrc + off, ldst + (p % 3) * 8192);
    };

    // fragment read offsets (swizzle folded in)
    int boffs[4];
    #pragma unroll
    for (int k = 0; k < 4; k++)
        boffs[k] = (((k << 6) | (lhi << 4)) ^ ((lr & 7) << 4));

    auto compute = [&](int slot, int half, int j) {
        const char* brow = lbase + slot * 8192 + half * 4096 + lr * 256;
        bf16x8 bfrag[4];
        #pragma unroll
        for (int k = 0; k < 4; k++)
            bfrag[k] = *reinterpret_cast<const bf16x8*>(brow + boffs[k]);
        f32x4 acc[4];
        #pragma unroll
        for (int m = 0; m < 4; m++) acc[m] = (f32x4){0.f, 0.f, 0.f, 0.f};
        __builtin_amdgcn_s_setprio(1);
        #pragma unroll
        for (int k = 0; k < 4; k++)
            #pragma unroll
            for (int m = 0; m < 4; m++)
                acc[m] = __builtin_amdgcn_mfma_f32_16x16x32_bf16(
                    pfrag[m][k], bfrag[k], acc[m], 0, 0, 0);
        __builtin_amdgcn_s_setprio(0);
        // per-lane max over its 16 patches; m=3: only patch 48 (lhi==0, reg 0) real
        float x0 = fmaxf(acc[0][0], acc[0][1]);
        float x1 = fmaxf(acc[0][2], acc[0][3]);
        float x2 = fmaxf(acc[1][0], acc[1][1]);
        float x3 = fmaxf(acc[1][2], acc[1][3]);
        float x4 = fmaxf(acc[2][0], acc[2][1]);
        float x5 = fmaxf(acc[2][2], acc[2][3]);
        float x6 = (lhi == 0) ? acc[3][0] : -3e38f;
        x0 = fmaxf(x0, x1);
        x2 = fmaxf(x2, x3);
        x4 = fmaxf(x4, x5);
        x0 = fmaxf(x0, x2);
        x4 = fmaxf(x4, x6);
        vals[wave][j][lane] = fmaxf(x0, x4);
    };

    stage(0);
    stage(1);
    // Phases P=0..12 over pairs; per phase: counted vmcnt (stage(P) landed,
    // stage(P+1) may fly) -> barrier -> read frags -> issue stage(P+2) -> MFMA.
    // WAR safety on slot (P+2)%3=(P-1)%3: every wave's phase-(P-1) ds_reads are
    // lgkm-drained before its MFMAs, which precede its barrier-P arrival.
    #pragma unroll 1
    for (int p = 0; p < 11; p++) {
        asm volatile("s_waitcnt vmcnt(1)" ::: "memory");
        __builtin_amdgcn_s_barrier();
        asm volatile("" ::: "memory");
        stage(p + 2);
        compute(p % 3, 0, 2 * p);
        compute(p % 3, 1, 2 * p + 1);
    }
    asm volatile("s_waitcnt vmcnt(1)" ::: "memory");   // P=11
    __builtin_amdgcn_s_barrier();
    asm volatile("" ::: "memory");
    compute(2, 0, 22);
    compute(2, 1, 23);
    asm volatile("s_waitcnt vmcnt(0)" ::: "memory");   // P=12 (tile 24)
    __builtin_amdgcn_s_barrier();
    asm volatile("" ::: "memory");
    compute(0, 0, 24);
    __syncthreads();

    // Epilogue: cross-lane max + length-25 sum + scale; 128 outputs per WG.
    if (tid < 8 * CH_T) {
        int g  = tid >> 4;
        int tl = tid & 15;
        float s = 0.f;
        #pragma unroll
        for (int l = 0; l < 25; l++) {
            int row = tl * 25 + l;          // text row within chunk, 0..399
            int j = row >> 4;
            int r = row & 15;
            float m0 = fmaxf(vals[g][j][r],      vals[g][j][r + 16]);
            float m1 = fmaxf(vals[g][j][r + 32], vals[g][j][r + 48]);
            s += fmaxf(m0, m1);
        }
        int t = tq * CH_T + tl;
        int i = ig * WAVES + g;
        float val = s / (float)text_length[t] * expf(logit_scale[0]);
        out[(size_t)i * NT + t] = val;                      // logits_per_image [I,T]
        out[(size_t)NI * NT + (size_t)t * NI + i] = val;    // logits_per_text  [T,I]
    }
}

extern "C" void kernel_launch(void* const* d_in, const int* in_sizes, int n_in,
                              void* d_out, int out_size, void* d_ws, size_t ws_size,
                              hipStream_t stream)
{
    const float* img  = (const float*)d_in[0];   // [256,128,7,7]
    const float* emb  = (const float*)d_in[1];   // [10000,128]
    const float* ls   = (const float*)d_in[2];   // scalar
    const int*   text = (const int*)d_in[3];     // [256,25]
    const int*   tlen = (const int*)d_in[4];     // [256]
    float* out = (float*)d_out;

    __hip_bfloat16* tf2 = (__hip_bfloat16*)d_ws;                                  // 1,638,400 B
    __hip_bfloat16* P2  = (__hip_bfloat16*)((char*)d_ws + (size_t)NTL * NE * 2);  // 4,194,304 B

    prep_kernel<<<400 + NI, 256, 0, stream>>>(emb, text, img, tf2, P2);
    match_kernel<<<512, 512, 0, stream>>>(tf2, P2, tlen, ls, out);
}